// Round 1
// baseline (2831.844 us; speedup 1.0000x reference)
//
#include <hip/hip_runtime.h>

#define B_ 16
#define C_ 1024
#define D_ 1024
#define H_ 64
#define M_ (B_*C_)   // 16384

__device__ __forceinline__ float wave_max(float v){
  #pragma unroll
  for (int o = 32; o > 0; o >>= 1) v = fmaxf(v, __shfl_xor(v, o));
  return v;
}
__device__ __forceinline__ float wave_sum(float v){
  #pragma unroll
  for (int o = 32; o > 0; o >>= 1) v += __shfl_xor(v, o);
  return v;
}

// Out[m,n] = relu(sum_k A[m,k]*W[k,n] + bias[n]); A:[M_,1024] W:[1024,1024]
__global__ __launch_bounds__(256) void gemm_relu_kernel(
    const float* __restrict__ A, const float* __restrict__ W,
    const float* __restrict__ bias, float* __restrict__ Out)
{
  __shared__ float As[64][17];   // [m][k], pad -> conflict-free strided reads
  __shared__ float Bs[16][64];   // [k][n]
  const int t  = threadIdx.x;
  const int tn = t & 15, tm = t >> 4;
  const int bn = blockIdx.x, bm = blockIdx.y;
  const int arow = t >> 2,  acol = (t & 3) * 4;
  const int brow = t >> 4,  bcol = (t & 15) * 4;
  const float* Ag = A + (size_t)(bm*64 + arow)*D_ + acol;
  const float* Wg = W + (size_t)brow*D_ + bn*64 + bcol;
  float acc[4][4] = {};
  for (int k0 = 0; k0 < D_; k0 += 16) {
    float4 av = *(const float4*)(Ag + k0);
    float4 bv = *(const float4*)(Wg + (size_t)k0*D_);
    As[arow][acol+0] = av.x; As[arow][acol+1] = av.y;
    As[arow][acol+2] = av.z; As[arow][acol+3] = av.w;
    *(float4*)&Bs[brow][bcol] = bv;
    __syncthreads();
    #pragma unroll
    for (int kk = 0; kk < 16; ++kk) {
      float a0 = As[tm*4+0][kk], a1 = As[tm*4+1][kk];
      float a2 = As[tm*4+2][kk], a3 = As[tm*4+3][kk];
      float4 b = *(float4*)&Bs[kk][tn*4];
      acc[0][0] += a0*b.x; acc[0][1] += a0*b.y; acc[0][2] += a0*b.z; acc[0][3] += a0*b.w;
      acc[1][0] += a1*b.x; acc[1][1] += a1*b.y; acc[1][2] += a1*b.z; acc[1][3] += a1*b.w;
      acc[2][0] += a2*b.x; acc[2][1] += a2*b.y; acc[2][2] += a2*b.z; acc[2][3] += a2*b.w;
      acc[3][0] += a3*b.x; acc[3][1] += a3*b.y; acc[3][2] += a3*b.z; acc[3][3] += a3*b.w;
    }
    __syncthreads();
  }
  const int n0 = bn*64 + tn*4;
  const float4 b4 = *(const float4*)&bias[n0];
  #pragma unroll
  for (int i = 0; i < 4; ++i) {
    const int m = bm*64 + tm*4 + i;
    float4 o;
    o.x = fmaxf(acc[i][0] + b4.x, 0.f);
    o.y = fmaxf(acc[i][1] + b4.y, 0.f);
    o.z = fmaxf(acc[i][2] + b4.z, 0.f);
    o.w = fmaxf(acc[i][3] + b4.w, 0.f);
    *(float4*)&Out[(size_t)m*D_ + n0] = o;
  }
}

// E'[bz][j][i] = sum_d k[b0+bz,j,d] * q[b0+bz,i,d]   (A@B^T, both row-major)
__global__ __launch_bounds__(256) void energy_kernel(
    const float* __restrict__ Km, const float* __restrict__ Qm,
    float* __restrict__ E, int b0)
{
  __shared__ float Ks[64][17];
  __shared__ float Qs[64][17];
  const int bz = blockIdx.z;
  const float* kb = Km + (size_t)(b0 + bz)*C_*D_;
  const float* qb = Qm + (size_t)(b0 + bz)*C_*D_;
  float* Eb = E + (size_t)bz*C_*C_;
  const int t  = threadIdx.x;
  const int tn = t & 15, tm = t >> 4;
  const int bi = blockIdx.x, bj = blockIdx.y;
  const int lrow = t >> 2, lcol = (t & 3)*4;
  const float* kg = kb + (size_t)(bj*64 + lrow)*D_ + lcol;
  const float* qg = qb + (size_t)(bi*64 + lrow)*D_ + lcol;
  float acc[4][4] = {};
  for (int k0 = 0; k0 < D_; k0 += 16) {
    float4 kv = *(const float4*)(kg + k0);
    float4 qv = *(const float4*)(qg + k0);
    Ks[lrow][lcol+0] = kv.x; Ks[lrow][lcol+1] = kv.y;
    Ks[lrow][lcol+2] = kv.z; Ks[lrow][lcol+3] = kv.w;
    Qs[lrow][lcol+0] = qv.x; Qs[lrow][lcol+1] = qv.y;
    Qs[lrow][lcol+2] = qv.z; Qs[lrow][lcol+3] = qv.w;
    __syncthreads();
    #pragma unroll
    for (int kk = 0; kk < 16; ++kk) {
      float ka0 = Ks[tm*4+0][kk], ka1 = Ks[tm*4+1][kk];
      float ka2 = Ks[tm*4+2][kk], ka3 = Ks[tm*4+3][kk];
      float qa0 = Qs[tn*4+0][kk], qa1 = Qs[tn*4+1][kk];
      float qa2 = Qs[tn*4+2][kk], qa3 = Qs[tn*4+3][kk];
      acc[0][0] += ka0*qa0; acc[0][1] += ka0*qa1; acc[0][2] += ka0*qa2; acc[0][3] += ka0*qa3;
      acc[1][0] += ka1*qa0; acc[1][1] += ka1*qa1; acc[1][2] += ka1*qa2; acc[1][3] += ka1*qa3;
      acc[2][0] += ka2*qa0; acc[2][1] += ka2*qa1; acc[2][2] += ka2*qa2; acc[2][3] += ka2*qa3;
      acc[3][0] += ka3*qa0; acc[3][1] += ka3*qa1; acc[3][2] += ka3*qa2; acc[3][3] += ka3*qa3;
    }
    __syncthreads();
  }
  const int i0 = bi*64 + tn*4;
  #pragma unroll
  for (int a = 0; a < 4; ++a) {
    const int j = bj*64 + tm*4 + a;
    float4 o; o.x = acc[a][0]; o.y = acc[a][1]; o.z = acc[a][2]; o.w = acc[a][3];
    *(float4*)&Eb[(size_t)j*C_ + i0] = o;
  }
}

// row softmax over i (contiguous), then scale row j by w[b,j]; in place
__global__ __launch_bounds__(256) void attn_softmax_kernel(
    float* __restrict__ E, const float* __restrict__ w, int b0)
{
  __shared__ float redm[4];
  __shared__ float reds[4];
  const int j = blockIdx.x, bz = blockIdx.y;
  float* row = E + (size_t)bz*C_*C_ + (size_t)j*C_;
  const int t = threadIdx.x;
  const int lane = t & 63, wid = t >> 6;
  float4 v = *(const float4*)&row[t*4];
  float m = fmaxf(fmaxf(v.x, v.y), fmaxf(v.z, v.w));
  m = wave_max(m);
  if (lane == 0) redm[wid] = m;
  __syncthreads();
  m = fmaxf(fmaxf(redm[0], redm[1]), fmaxf(redm[2], redm[3]));
  float e0 = expf(v.x - m), e1 = expf(v.y - m);
  float e2 = expf(v.z - m), e3 = expf(v.w - m);
  float s = e0 + e1 + e2 + e3;
  s = wave_sum(s);
  if (lane == 0) reds[wid] = s;
  __syncthreads();
  s = reds[0] + reds[1] + reds[2] + reds[3];
  const float scale = w[(size_t)(b0 + bz)*C_ + j] / s;
  float4 o; o.x = e0*scale; o.y = e1*scale; o.z = e2*scale; o.w = e3*scale;
  *(float4*)&row[t*4] = o;
}

// u[b,i] = sum_j Escaled[j,i]
__global__ __launch_bounds__(256) void colsum_kernel(
    const float* __restrict__ E, float* __restrict__ u, int b0)
{
  const int i = blockIdx.x*256 + threadIdx.x;
  const float* Eb = E + (size_t)blockIdx.y*C_*C_;
  float s = 0.f;
  #pragma unroll 4
  for (int j = 0; j < C_; ++j) s += Eb[(size_t)j*C_ + i];
  u[(size_t)(b0 + blockIdx.y)*C_ + i] = s;
}

// e2[m] = sum_h relu(x[m]@W1[:,h] + b1[h]) * W2[h]   (b2 cancels in softmax)
__global__ __launch_bounds__(256) void pool_kernel(
    const float* __restrict__ X, const float* __restrict__ W1,
    const float* __restrict__ b1, const float* __restrict__ W2,
    float* __restrict__ e2out)
{
  __shared__ float xs[16][64];
  __shared__ float w1s[64][64];   // [k][h]
  const int t = threadIdx.x;
  const int h = t & 63, rg = t >> 6;
  const int row0 = blockIdx.x * 16;
  float acc[4] = {};
  for (int k0 = 0; k0 < D_; k0 += 64) {
    *(float4*)&xs[t>>4][(t&15)*4] =
        *(const float4*)&X[(size_t)(row0 + (t>>4))*D_ + k0 + (t&15)*4];
    #pragma unroll
    for (int i = 0; i < 16; ++i)
      w1s[rg + i*4][h] = W1[(size_t)(k0 + rg + i*4)*H_ + h];
    __syncthreads();
    #pragma unroll
    for (int kk = 0; kk < 64; ++kk) {
      const float wv = w1s[kk][h];
      acc[0] += xs[rg*4+0][kk] * wv;
      acc[1] += xs[rg*4+1][kk] * wv;
      acc[2] += xs[rg*4+2][kk] * wv;
      acc[3] += xs[rg*4+3][kk] * wv;
    }
    __syncthreads();
  }
  const float b1h = b1[h], w2h = W2[h];
  #pragma unroll
  for (int r = 0; r < 4; ++r) {
    float val = fmaxf(acc[r] + b1h, 0.f) * w2h;
    val = wave_sum(val);
    if (h == 0) e2out[row0 + rg*4 + r] = val;
  }
}

__global__ __launch_bounds__(256) void softmax_w_kernel(
    const float* __restrict__ e2in, float* __restrict__ w)
{
  __shared__ float redm[4];
  __shared__ float reds[4];
  const int b = blockIdx.x, t = threadIdx.x;
  const int lane = t & 63, wid = t >> 6;
  const float* row = e2in + (size_t)b*C_;
  float4 v = *(const float4*)&row[t*4];
  float m = fmaxf(fmaxf(v.x, v.y), fmaxf(v.z, v.w));
  m = wave_max(m);
  if (lane == 0) redm[wid] = m;
  __syncthreads();
  m = fmaxf(fmaxf(redm[0], redm[1]), fmaxf(redm[2], redm[3]));
  float e0 = expf(v.x - m), e1 = expf(v.y - m);
  float e2 = expf(v.z - m), e3 = expf(v.w - m);
  float s = e0 + e1 + e2 + e3;
  s = wave_sum(s);
  if (lane == 0) reds[wid] = s;
  __syncthreads();
  s = reds[0] + reds[1] + reds[2] + reds[3];
  const float inv = 1.0f / s;
  float4 o; o.x = e0*inv; o.y = e1*inv; o.z = e2*inv; o.w = e3*inv;
  *(float4*)&w[(size_t)b*C_ + t*4] = o;
}

// out[b,d] = gamma * sum_i u[b,i]*v[b,i,d] + sum_i w[b,i]*x[b,i,d]
__global__ __launch_bounds__(256) void final_kernel(
    const float* __restrict__ X, const float* __restrict__ V,
    const float* __restrict__ u, const float* __restrict__ w,
    const float* __restrict__ gamma, float* __restrict__ out)
{
  const int b = blockIdx.y;
  const int d = blockIdx.x*256 + threadIdx.x;
  const float* xb = X + (size_t)b*C_*D_ + d;
  const float* vb = V + (size_t)b*C_*D_ + d;
  const float* ub = u + (size_t)b*C_;
  const float* wb = w + (size_t)b*C_;
  float accv = 0.f, accx = 0.f;
  #pragma unroll 4
  for (int i = 0; i < C_; ++i) {
    accv += ub[i] * vb[(size_t)i*D_];
    accx += wb[i] * xb[(size_t)i*D_];
  }
  out[(size_t)b*D_ + d] = gamma[0]*accv + accx;
}

extern "C" void kernel_launch(void* const* d_in, const int* in_sizes, int n_in,
                              void* d_out, int out_size, void* d_ws, size_t ws_size,
                              hipStream_t stream) {
  (void)in_sizes; (void)n_in; (void)out_size;
  const float* x  = (const float*)d_in[0];
  const float* Wf = (const float*)d_in[1];
  const float* bf = (const float*)d_in[2];
  const float* Wg = (const float*)d_in[3];
  const float* bg = (const float*)d_in[4];
  const float* Wx = (const float*)d_in[5];
  const float* bx = (const float*)d_in[6];
  const float* W1 = (const float*)d_in[7];
  const float* b1 = (const float*)d_in[8];
  const float* W2 = (const float*)d_in[9];
  const float* gamma = (const float*)d_in[11];
  float* out = (float*)d_out;

  char* ws = (char*)d_ws;
  const size_t sz_mat = (size_t)M_ * D_ * sizeof(float);     // 64 MiB
  float* q    = (float*)ws;
  float* k    = (float*)(ws + sz_mat);
  float* v    = (float*)(ws + 2*sz_mat);
  float* e2b  = (float*)(ws + 3*sz_mat);
  float* wbuf = e2b + M_;
  float* u    = wbuf + M_;
  float* E    = u + M_;
  const size_t base   = 3*sz_mat + 3*(size_t)M_*sizeof(float);
  const size_t ebytes = (size_t)C_*C_*sizeof(float);         // 4 MiB / batch
  int chunkB = (ws_size > base) ? (int)((ws_size - base) / ebytes) : 1;
  if (chunkB > B_) chunkB = B_;
  if (chunkB < 1) chunkB = 1;

  gemm_relu_kernel<<<dim3(16,256),256,0,stream>>>(x, Wf, bf, q);
  gemm_relu_kernel<<<dim3(16,256),256,0,stream>>>(x, Wg, bg, k);
  gemm_relu_kernel<<<dim3(16,256),256,0,stream>>>(x, Wx, bx, v);
  pool_kernel<<<dim3(M_/16),256,0,stream>>>(x, W1, b1, W2, e2b);
  softmax_w_kernel<<<dim3(B_),256,0,stream>>>(e2b, wbuf);
  for (int b0 = 0; b0 < B_; b0 += chunkB) {
    const int nb = (B_ - b0 < chunkB) ? (B_ - b0) : chunkB;
    energy_kernel<<<dim3(16,16,nb),256,0,stream>>>(k, q, E, b0);
    attn_softmax_kernel<<<dim3(C_,nb),256,0,stream>>>(E, wbuf, b0);
    colsum_kernel<<<dim3(C_/256,nb),256,0,stream>>>(E, u, b0);
  }
  final_kernel<<<dim3(D_/256,B_),256,0,stream>>>(x, v, u, wbuf, gamma, out);
}

// Round 2
// 695.358 us; speedup vs baseline: 4.0725x; 4.0725x over previous
//
#include <hip/hip_runtime.h>

#define B_ 16
#define C_ 1024
#define D_ 1024
#define H_ 64
#define M_ (B_*C_)   // 16384

typedef __attribute__((ext_vector_type(8))) short bf16x8;
typedef __attribute__((ext_vector_type(4))) float f32x4;

__device__ __forceinline__ float wave_max(float v){
  #pragma unroll
  for (int o = 32; o > 0; o >>= 1) v = fmaxf(v, __shfl_xor(v, o));
  return v;
}
__device__ __forceinline__ float wave_sum(float v){
  #pragma unroll
  for (int o = 32; o > 0; o >>= 1) v += __shfl_xor(v, o);
  return v;
}

// fp32 -> bf16 (RNE)
__device__ __forceinline__ ushort f2bf(float f){
  union { float f; unsigned u; } a; a.f = f;
  unsigned r = a.u + 0x7fff + ((a.u >> 16) & 1);
  return (ushort)(r >> 16);
}

// async global->LDS, 16 B per lane. lds dest must be wave-uniform base.
__device__ __forceinline__ void lds_cp16(const ushort* g, ushort* l){
  __builtin_amdgcn_global_load_lds(
      (const __attribute__((address_space(1))) void*)g,
      (__attribute__((address_space(3))) void*)l, 16, 0, 0);
}

// ---------------- conversion kernels ----------------

__global__ __launch_bounds__(256) void cvt_kernel(
    const float* __restrict__ in, ushort* __restrict__ out, int n4)
{
  int i = blockIdx.x*256 + threadIdx.x;
  if (i >= n4) return;
  float4 v = ((const float4*)in)[i];
  ushort4 o;
  o.x = f2bf(v.x); o.y = f2bf(v.y); o.z = f2bf(v.z); o.w = f2bf(v.w);
  ((ushort4*)out)[i] = o;
}

// Wt[n][k] = bf16(W[k][n]);  W: 1024x1024 row-major
__global__ __launch_bounds__(256) void tconv_kernel(
    const float* __restrict__ W, ushort* __restrict__ Wt)
{
  __shared__ float tile[32][33];
  const int t = threadIdx.x;
  const int tx = t & 31, ty = t >> 5;          // 32 x 8
  const int n0 = blockIdx.x*32, k0 = blockIdx.y*32;
  #pragma unroll
  for (int i = 0; i < 32; i += 8)
    tile[ty+i][tx] = W[(size_t)(k0+ty+i)*D_ + n0+tx];
  __syncthreads();
  #pragma unroll
  for (int i = 0; i < 32; i += 8)
    Wt[(size_t)(n0+ty+i)*D_ + k0+tx] = f2bf(tile[tx][ty+i]);
}

// ---------------- MFMA NT GEMM ----------------
// D[m][n] = sum_k A[m][k] * Bt[n][k]; A,Bt bf16 row-major, K=1024, N=1024.
// MODE 0: energy (f32 out, no bias);  1: relu(.+bias) -> bf16;  2: relu(.+bias) -> f32
template<int MODE>
__global__ __launch_bounds__(256) void mfma_nt_kernel(
    const ushort* __restrict__ A, const ushort* __restrict__ Bt,
    const float* __restrict__ bias, void* __restrict__ Out,
    size_t strideA, size_t strideB, size_t strideO)
{
  __shared__ ushort As[128*32];   // [row][k] row-major, no pad (global_load_lds)
  __shared__ ushort Bs[128*32];
  const int t = threadIdx.x;
  const int wid = t >> 6, lane = t & 63;
  const int m0 = blockIdx.y * 128, n0 = blockIdx.x * 128;
  const ushort* Ab = A + (size_t)blockIdx.z * strideA;
  const ushort* Bb = Bt + (size_t)blockIdx.z * strideB;

  // staging: thread t loads 16B at row t>>2 (within 64-row chunk), kgroup t&3
  const int r = t >> 2;
  const int kc = (t & 3) * 8;
  const ushort* ga0 = Ab + (size_t)(m0 + r)*1024 + kc;
  const ushort* ga1 = ga0 + (size_t)64*1024;
  const ushort* gb0 = Bb + (size_t)(n0 + r)*1024 + kc;
  const ushort* gb1 = gb0 + (size_t)64*1024;
  ushort* lA = As + wid*512;      // wave-uniform dest (1 KiB per wave-instr)
  ushort* lB = Bs + wid*512;

  const int quad = lane >> 4, l16 = lane & 15;
  const int wm = wid >> 1, wn = wid & 1;
  const int am0 = (wm*64 + l16)*32 + quad*8;
  const int bn0 = (wn*64 + l16)*32 + quad*8;

  f32x4 acc[4][4] = {};

  for (int k0 = 0; k0 < 1024; k0 += 32) {
    lds_cp16(ga0, lA); lds_cp16(ga1, lA + 2048);
    lds_cp16(gb0, lB); lds_cp16(gb1, lB + 2048);
    ga0 += 32; ga1 += 32; gb0 += 32; gb1 += 32;
    __syncthreads();   // drains vmcnt(0) -> LDS tiles ready
    bf16x8 af[4], bfr[4];
    #pragma unroll
    for (int i = 0; i < 4; ++i) {
      af[i]  = *(const bf16x8*)&As[am0 + i*512];   // A[m=l16][k=quad*8+j]
      bfr[i] = *(const bf16x8*)&Bs[bn0 + i*512];   // B[k][n=l16]
    }
    #pragma unroll
    for (int mt = 0; mt < 4; ++mt)
      #pragma unroll
      for (int nt = 0; nt < 4; ++nt)
        acc[mt][nt] = __builtin_amdgcn_mfma_f32_16x16x32_bf16(
            af[mt], bfr[nt], acc[mt][nt], 0, 0, 0);
    __syncthreads();   // LDS reads done before next staging overwrites
  }

  // C/D layout: col = lane&15, row = quad*4 + reg
  const int gm_base = m0 + wm*64 + quad*4;
  const int gn_base = n0 + wn*64 + l16;
  if (MODE == 0) {
    float* O = (float*)Out + (size_t)blockIdx.z * strideO;
    #pragma unroll
    for (int mt = 0; mt < 4; ++mt)
      #pragma unroll
      for (int rr = 0; rr < 4; ++rr) {
        const size_t rowoff = (size_t)(gm_base + mt*16 + rr) * 1024;
        #pragma unroll
        for (int nt = 0; nt < 4; ++nt)
          O[rowoff + gn_base + nt*16] = acc[mt][nt][rr];
      }
  } else {
    float bv[4];
    #pragma unroll
    for (int nt = 0; nt < 4; ++nt) bv[nt] = bias[gn_base + nt*16];
    #pragma unroll
    for (int mt = 0; mt < 4; ++mt)
      #pragma unroll
      for (int rr = 0; rr < 4; ++rr) {
        const size_t rowoff = (size_t)(gm_base + mt*16 + rr) * 1024;
        #pragma unroll
        for (int nt = 0; nt < 4; ++nt) {
          float v = fmaxf(acc[mt][nt][rr] + bv[nt], 0.f);
          if (MODE == 1) ((ushort*)Out)[rowoff + gn_base + nt*16] = f2bf(v);
          else           ((float*)Out)[rowoff + gn_base + nt*16] = v;
        }
      }
  }
}

// ---------------- softmax / pooling / reduction kernels (round-1, verified) ----------------

// row softmax over i (contiguous), then scale row j by w[b,j]; in place
__global__ __launch_bounds__(256) void attn_softmax_kernel(
    float* __restrict__ E, const float* __restrict__ w, int b0)
{
  __shared__ float redm[4];
  __shared__ float reds[4];
  const int j = blockIdx.x, bz = blockIdx.y;
  float* row = E + (size_t)bz*C_*C_ + (size_t)j*C_;
  const int t = threadIdx.x;
  const int lane = t & 63, wid = t >> 6;
  float4 v = *(const float4*)&row[t*4];
  float m = fmaxf(fmaxf(v.x, v.y), fmaxf(v.z, v.w));
  m = wave_max(m);
  if (lane == 0) redm[wid] = m;
  __syncthreads();
  m = fmaxf(fmaxf(redm[0], redm[1]), fmaxf(redm[2], redm[3]));
  float e0 = expf(v.x - m), e1 = expf(v.y - m);
  float e2 = expf(v.z - m), e3 = expf(v.w - m);
  float s = e0 + e1 + e2 + e3;
  s = wave_sum(s);
  if (lane == 0) reds[wid] = s;
  __syncthreads();
  s = reds[0] + reds[1] + reds[2] + reds[3];
  const float scale = w[(size_t)(b0 + bz)*C_ + j] / s;
  float4 o; o.x = e0*scale; o.y = e1*scale; o.z = e2*scale; o.w = e3*scale;
  *(float4*)&row[t*4] = o;
}

// u[b,i] = sum_j Escaled[j,i]
__global__ __launch_bounds__(256) void colsum_kernel(
    const float* __restrict__ E, float* __restrict__ u, int b0)
{
  const int i = blockIdx.x*256 + threadIdx.x;
  const float* Eb = E + (size_t)blockIdx.y*C_*C_;
  float s = 0.f;
  #pragma unroll 4
  for (int j = 0; j < C_; ++j) s += Eb[(size_t)j*C_ + i];
  u[(size_t)(b0 + blockIdx.y)*C_ + i] = s;
}

// e2[m] = sum_h relu(x[m]@W1[:,h] + b1[h]) * W2[h]
__global__ __launch_bounds__(256) void pool_kernel(
    const float* __restrict__ X, const float* __restrict__ W1,
    const float* __restrict__ b1, const float* __restrict__ W2,
    float* __restrict__ e2out)
{
  __shared__ float xs[16][64];
  __shared__ float w1s[64][64];
  const int t = threadIdx.x;
  const int h = t & 63, rg = t >> 6;
  const int row0 = blockIdx.x * 16;
  float acc[4] = {};
  for (int k0 = 0; k0 < D_; k0 += 64) {
    *(float4*)&xs[t>>4][(t&15)*4] =
        *(const float4*)&X[(size_t)(row0 + (t>>4))*D_ + k0 + (t&15)*4];
    #pragma unroll
    for (int i = 0; i < 16; ++i)
      w1s[rg + i*4][h] = W1[(size_t)(k0 + rg + i*4)*H_ + h];
    __syncthreads();
    #pragma unroll
    for (int kk = 0; kk < 64; ++kk) {
      const float wv = w1s[kk][h];
      acc[0] += xs[rg*4+0][kk] * wv;
      acc[1] += xs[rg*4+1][kk] * wv;
      acc[2] += xs[rg*4+2][kk] * wv;
      acc[3] += xs[rg*4+3][kk] * wv;
    }
    __syncthreads();
  }
  const float b1h = b1[h], w2h = W2[h];
  #pragma unroll
  for (int r = 0; r < 4; ++r) {
    float val = fmaxf(acc[r] + b1h, 0.f) * w2h;
    val = wave_sum(val);
    if (h == 0) e2out[row0 + rg*4 + r] = val;
  }
}

__global__ __launch_bounds__(256) void softmax_w_kernel(
    const float* __restrict__ e2in, float* __restrict__ w)
{
  __shared__ float redm[4];
  __shared__ float reds[4];
  const int b = blockIdx.x, t = threadIdx.x;
  const int lane = t & 63, wid = t >> 6;
  const float* row = e2in + (size_t)b*C_;
  float4 v = *(const float4*)&row[t*4];
  float m = fmaxf(fmaxf(v.x, v.y), fmaxf(v.z, v.w));
  m = wave_max(m);
  if (lane == 0) redm[wid] = m;
  __syncthreads();
  m = fmaxf(fmaxf(redm[0], redm[1]), fmaxf(redm[2], redm[3]));
  float e0 = expf(v.x - m), e1 = expf(v.y - m);
  float e2 = expf(v.z - m), e3 = expf(v.w - m);
  float s = e0 + e1 + e2 + e3;
  s = wave_sum(s);
  if (lane == 0) reds[wid] = s;
  __syncthreads();
  s = reds[0] + reds[1] + reds[2] + reds[3];
  const float inv = 1.0f / s;
  float4 o; o.x = e0*inv; o.y = e1*inv; o.z = e2*inv; o.w = e3*inv;
  *(float4*)&w[(size_t)b*C_ + t*4] = o;
}

// out[b,d] = gamma * sum_i u[b,i]*v[b,i,d] + sum_i w[b,i]*x[b,i,d]
__global__ __launch_bounds__(256) void final_kernel(
    const float* __restrict__ X, const float* __restrict__ V,
    const float* __restrict__ u, const float* __restrict__ w,
    const float* __restrict__ gamma, float* __restrict__ out)
{
  const int b = blockIdx.y;
  const int d = blockIdx.x*256 + threadIdx.x;
  const float* xb = X + (size_t)b*C_*D_ + d;
  const float* vb = V + (size_t)b*C_*D_ + d;
  const float* ub = u + (size_t)b*C_;
  const float* wb = w + (size_t)b*C_;
  float accv = 0.f, accx = 0.f;
  #pragma unroll 4
  for (int i = 0; i < C_; ++i) {
    accv += ub[i] * vb[(size_t)i*D_];
    accx += wb[i] * xb[(size_t)i*D_];
  }
  out[(size_t)b*D_ + d] = gamma[0]*accv + accx;
}

extern "C" void kernel_launch(void* const* d_in, const int* in_sizes, int n_in,
                              void* d_out, int out_size, void* d_ws, size_t ws_size,
                              hipStream_t stream) {
  (void)in_sizes; (void)n_in; (void)out_size;
  const float* x  = (const float*)d_in[0];
  const float* Wf = (const float*)d_in[1];
  const float* bf = (const float*)d_in[2];
  const float* Wg = (const float*)d_in[3];
  const float* bg = (const float*)d_in[4];
  const float* Wx = (const float*)d_in[5];
  const float* bx = (const float*)d_in[6];
  const float* W1 = (const float*)d_in[7];
  const float* b1 = (const float*)d_in[8];
  const float* W2 = (const float*)d_in[9];
  const float* gamma = (const float*)d_in[11];
  float* out = (float*)d_out;

  // workspace layout
  ushort* x_bf = (ushort*)d_ws;                  // 32 MB
  ushort* wtf  = x_bf + (size_t)M_*D_;           // 2 MB
  ushort* wtg  = wtf + (size_t)D_*D_;
  ushort* wtx  = wtg + (size_t)D_*D_;
  ushort* q_bf = wtx + (size_t)D_*D_;            // 32 MB
  ushort* k_bf = q_bf + (size_t)M_*D_;           // 32 MB
  float*  v    = (float*)(k_bf + (size_t)M_*D_); // 64 MB
  float*  e2b  = v + (size_t)M_*D_;
  float*  wbuf = e2b + M_;
  float*  u    = wbuf + M_;
  float*  E    = u + M_;
  const size_t base = (size_t)(32+2+2+2+32+32+64)*1024*1024 + 3*(size_t)M_*sizeof(float);
  const size_t ebytes = (size_t)C_*C_*sizeof(float);   // 4 MiB / batch
  int chunkB = (ws_size > base) ? (int)((ws_size - base) / ebytes) : 1;
  if (chunkB > B_) chunkB = B_;
  if (chunkB < 1) chunkB = 1;

  // bf16 conversions
  cvt_kernel<<<dim3((M_*D_/4 + 255)/256), 256, 0, stream>>>(x, x_bf, M_*D_/4);
  tconv_kernel<<<dim3(32,32), 256, 0, stream>>>(Wf, wtf);
  tconv_kernel<<<dim3(32,32), 256, 0, stream>>>(Wg, wtg);
  tconv_kernel<<<dim3(32,32), 256, 0, stream>>>(Wx, wtx);

  // projections (bf16 MFMA): q,k -> bf16, v -> f32
  mfma_nt_kernel<1><<<dim3(8,128,1), 256, 0, stream>>>(x_bf, wtf, bf, q_bf, 0,0,0);
  mfma_nt_kernel<1><<<dim3(8,128,1), 256, 0, stream>>>(x_bf, wtg, bg, k_bf, 0,0,0);
  mfma_nt_kernel<2><<<dim3(8,128,1), 256, 0, stream>>>(x_bf, wtx, bx, v,    0,0,0);

  // pooling weights
  pool_kernel<<<dim3(M_/16), 256, 0, stream>>>(x, W1, b1, W2, e2b);
  softmax_w_kernel<<<dim3(B_), 256, 0, stream>>>(e2b, wbuf);

  // energy (bf16 MFMA) + softmax + colsum, chunked over batch
  for (int b0 = 0; b0 < B_; b0 += chunkB) {
    const int nb = (B_ - b0 < chunkB) ? (B_ - b0) : chunkB;
    mfma_nt_kernel<0><<<dim3(8,8,nb), 256, 0, stream>>>(
        k_bf + (size_t)b0*C_*D_, q_bf + (size_t)b0*C_*D_, nullptr, E,
        (size_t)C_*D_, (size_t)C_*D_, (size_t)C_*C_);
    attn_softmax_kernel<<<dim3(C_,nb), 256, 0, stream>>>(E, wbuf, b0);
    colsum_kernel<<<dim3(C_/256,nb), 256, 0, stream>>>(E, u, b0);
  }
  final_kernel<<<dim3(D_/256,B_), 256, 0, stream>>>(x, v, u, wbuf, gamma, out);
}

// Round 3
// 496.102 us; speedup vs baseline: 5.7082x; 1.4016x over previous
//
#include <hip/hip_runtime.h>

#define B_ 16
#define C_ 1024
#define D_ 1024
#define H_ 64
#define M_ (B_*C_)   // 16384

typedef __attribute__((ext_vector_type(8))) short bf16x8;
typedef __attribute__((ext_vector_type(4))) float f32x4;

__device__ __forceinline__ float wave_max(float v){
  #pragma unroll
  for (int o = 32; o > 0; o >>= 1) v = fmaxf(v, __shfl_xor(v, o));
  return v;
}
__device__ __forceinline__ float wave_sum(float v){
  #pragma unroll
  for (int o = 32; o > 0; o >>= 1) v += __shfl_xor(v, o);
  return v;
}

// fp32 -> bf16 (RNE)
__device__ __forceinline__ ushort f2bf(float f){
  union { float f; unsigned u; } a; a.f = f;
  unsigned r = a.u + 0x7fff + ((a.u >> 16) & 1);
  return (ushort)(r >> 16);
}

// async global->LDS, 16 B per lane. lds dest must be wave-uniform base.
__device__ __forceinline__ void lds_cp16(const ushort* g, ushort* l){
  __builtin_amdgcn_global_load_lds(
      (const __attribute__((address_space(1))) void*)g,
      (__attribute__((address_space(3))) void*)l, 16, 0, 0);
}

// ---------------- conversion kernels ----------------

__global__ __launch_bounds__(256) void cvt_kernel(
    const float* __restrict__ in, ushort* __restrict__ out, int n4)
{
  int i = blockIdx.x*256 + threadIdx.x;
  if (i >= n4) return;
  float4 v = ((const float4*)in)[i];
  ushort4 o;
  o.x = f2bf(v.x); o.y = f2bf(v.y); o.z = f2bf(v.z); o.w = f2bf(v.w);
  ((ushort4*)out)[i] = o;
}

// Wt[n][k] = bf16(W[k][n]);  W: 1024x1024 row-major
__global__ __launch_bounds__(256) void tconv_kernel(
    const float* __restrict__ W, ushort* __restrict__ Wt)
{
  __shared__ float tile[32][33];
  const int t = threadIdx.x;
  const int tx = t & 31, ty = t >> 5;          // 32 x 8
  const int n0 = blockIdx.x*32, k0 = blockIdx.y*32;
  #pragma unroll
  for (int i = 0; i < 32; i += 8)
    tile[ty+i][tx] = W[(size_t)(k0+ty+i)*D_ + n0+tx];
  __syncthreads();
  #pragma unroll
  for (int i = 0; i < 32; i += 8)
    Wt[(size_t)(n0+ty+i)*D_ + k0+tx] = f2bf(tile[tx][ty+i]);
}

// ---------------- MFMA NT GEMM ----------------
// D[m][n] = sum_k A[m][k] * Bt[n][k]; A,Bt bf16 row-major, K=1024, N=1024.
// MODE 0: energy (f32 out, no bias);  1: relu(.+bias) -> bf16;  2: relu(.+bias) -> f32
template<int MODE>
__global__ __launch_bounds__(256) void mfma_nt_kernel(
    const ushort* __restrict__ A, const ushort* __restrict__ Bt,
    const float* __restrict__ bias, void* __restrict__ Out,
    size_t strideA, size_t strideB, size_t strideO)
{
  __shared__ ushort As[128*32];   // [row][k] row-major, no pad (global_load_lds)
  __shared__ ushort Bs[128*32];
  const int t = threadIdx.x;
  const int wid = t >> 6, lane = t & 63;
  const int m0 = blockIdx.y * 128, n0 = blockIdx.x * 128;
  const ushort* Ab = A + (size_t)blockIdx.z * strideA;
  const ushort* Bb = Bt + (size_t)blockIdx.z * strideB;

  const int r = t >> 2;
  const int kc = (t & 3) * 8;
  const ushort* ga0 = Ab + (size_t)(m0 + r)*1024 + kc;
  const ushort* ga1 = ga0 + (size_t)64*1024;
  const ushort* gb0 = Bb + (size_t)(n0 + r)*1024 + kc;
  const ushort* gb1 = gb0 + (size_t)64*1024;
  ushort* lA = As + wid*512;
  ushort* lB = Bs + wid*512;

  const int quad = lane >> 4, l16 = lane & 15;
  const int wm = wid >> 1, wn = wid & 1;
  const int am0 = (wm*64 + l16)*32 + quad*8;
  const int bn0 = (wn*64 + l16)*32 + quad*8;

  f32x4 acc[4][4] = {};

  for (int k0 = 0; k0 < 1024; k0 += 32) {
    lds_cp16(ga0, lA); lds_cp16(ga1, lA + 2048);
    lds_cp16(gb0, lB); lds_cp16(gb1, lB + 2048);
    ga0 += 32; ga1 += 32; gb0 += 32; gb1 += 32;
    __syncthreads();
    bf16x8 af[4], bfr[4];
    #pragma unroll
    for (int i = 0; i < 4; ++i) {
      af[i]  = *(const bf16x8*)&As[am0 + i*512];
      bfr[i] = *(const bf16x8*)&Bs[bn0 + i*512];
    }
    #pragma unroll
    for (int mt = 0; mt < 4; ++mt)
      #pragma unroll
      for (int nt = 0; nt < 4; ++nt)
        acc[mt][nt] = __builtin_amdgcn_mfma_f32_16x16x32_bf16(
            af[mt], bfr[nt], acc[mt][nt], 0, 0, 0);
    __syncthreads();
  }

  const int gm_base = m0 + wm*64 + quad*4;
  const int gn_base = n0 + wn*64 + l16;
  if (MODE == 0) {
    float* O = (float*)Out + (size_t)blockIdx.z * strideO;
    #pragma unroll
    for (int mt = 0; mt < 4; ++mt)
      #pragma unroll
      for (int rr = 0; rr < 4; ++rr) {
        const size_t rowoff = (size_t)(gm_base + mt*16 + rr) * 1024;
        #pragma unroll
        for (int nt = 0; nt < 4; ++nt)
          O[rowoff + gn_base + nt*16] = acc[mt][nt][rr];
      }
  } else {
    float bv[4];
    #pragma unroll
    for (int nt = 0; nt < 4; ++nt) bv[nt] = bias[gn_base + nt*16];
    #pragma unroll
    for (int mt = 0; mt < 4; ++mt)
      #pragma unroll
      for (int rr = 0; rr < 4; ++rr) {
        const size_t rowoff = (size_t)(gm_base + mt*16 + rr) * 1024;
        #pragma unroll
        for (int nt = 0; nt < 4; ++nt) {
          float v = fmaxf(acc[mt][nt][rr] + bv[nt], 0.f);
          if (MODE == 1) ((ushort*)Out)[rowoff + gn_base + nt*16] = f2bf(v);
          else           ((float*)Out)[rowoff + gn_base + nt*16] = v;
        }
      }
  }
}

// ---------------- fused row-softmax + weighted column-sum ----------------
// For strip of 16 rows j: u_part[strip][b][i] = sum_j w[b,j]*softmax_i(E'[b,j,:])[i]
// One wave per row (4 rows/wave), no barriers in the row loop.
__global__ __launch_bounds__(256) void fused_sm_kernel(
    const float* __restrict__ E, const float* __restrict__ w,
    float* __restrict__ u_part, int b0)
{
  __shared__ float ul[4][1024];
  const int bz = blockIdx.y;
  const int strip = blockIdx.x;       // 0..63
  const int t = threadIdx.x, wv = t >> 6, lane = t & 63;
  const float* Eb = E + (size_t)bz*C_*C_;
  const float* wb = w + (size_t)(b0+bz)*C_;
  float acc[4][4] = {};               // i = c*256 + lane*4 + k
  #pragma unroll
  for (int rj = 0; rj < 4; ++rj) {
    const int j = strip*16 + wv*4 + rj;
    const float* row = Eb + (size_t)j*C_;
    float4 v[4];
    float m = -1e30f;
    #pragma unroll
    for (int c = 0; c < 4; ++c) {
      v[c] = *(const float4*)&row[c*256 + lane*4];
      m = fmaxf(m, fmaxf(fmaxf(v[c].x, v[c].y), fmaxf(v[c].z, v[c].w)));
    }
    m = wave_max(m);
    float e[4][4];
    float s = 0.f;
    #pragma unroll
    for (int c = 0; c < 4; ++c) {
      e[c][0] = expf(v[c].x - m); e[c][1] = expf(v[c].y - m);
      e[c][2] = expf(v[c].z - m); e[c][3] = expf(v[c].w - m);
      s += e[c][0] + e[c][1] + e[c][2] + e[c][3];
    }
    s = wave_sum(s);
    const float sc = wb[j] / s;
    #pragma unroll
    for (int c = 0; c < 4; ++c)
      #pragma unroll
      for (int k2 = 0; k2 < 4; ++k2) acc[c][k2] += sc * e[c][k2];
  }
  #pragma unroll
  for (int c = 0; c < 4; ++c) {
    float4 o; o.x = acc[c][0]; o.y = acc[c][1]; o.z = acc[c][2]; o.w = acc[c][3];
    *(float4*)&ul[wv][c*256 + lane*4] = o;
  }
  __syncthreads();
  float4 r0 = *(float4*)&ul[0][t*4];
  float4 r1 = *(float4*)&ul[1][t*4];
  float4 r2 = *(float4*)&ul[2][t*4];
  float4 r3 = *(float4*)&ul[3][t*4];
  float4 o;
  o.x = r0.x+r1.x+r2.x+r3.x; o.y = r0.y+r1.y+r2.y+r3.y;
  o.z = r0.z+r1.z+r2.z+r3.z; o.w = r0.w+r1.w+r2.w+r3.w;
  *(float4*)&u_part[((size_t)strip*B_ + (b0+bz))*C_ + t*4] = o;
}

// u[b,i] = sum_{strip<64} u_part[strip][b][i]
__global__ __launch_bounds__(256) void u_combine_kernel(
    const float* __restrict__ u_part, float* __restrict__ u)
{
  const int idx = blockIdx.x*256 + threadIdx.x;   // over B_*C_
  float s = 0.f;
  #pragma unroll 8
  for (int sp = 0; sp < 64; ++sp) s += u_part[(size_t)sp*B_*C_ + idx];
  u[idx] = s;
}

// ---------------- pooling MLP ----------------

__global__ __launch_bounds__(256) void pool_kernel(
    const float* __restrict__ X, const float* __restrict__ W1,
    const float* __restrict__ b1, const float* __restrict__ W2,
    float* __restrict__ e2out)
{
  __shared__ float xs[16][64];
  __shared__ float w1s[64][64];
  const int t = threadIdx.x;
  const int h = t & 63, rg = t >> 6;
  const int row0 = blockIdx.x * 16;
  float acc[4] = {};
  for (int k0 = 0; k0 < D_; k0 += 64) {
    *(float4*)&xs[t>>4][(t&15)*4] =
        *(const float4*)&X[(size_t)(row0 + (t>>4))*D_ + k0 + (t&15)*4];
    #pragma unroll
    for (int i = 0; i < 16; ++i)
      w1s[rg + i*4][h] = W1[(size_t)(k0 + rg + i*4)*H_ + h];
    __syncthreads();
    #pragma unroll
    for (int kk = 0; kk < 64; ++kk) {
      const float wv = w1s[kk][h];
      acc[0] += xs[rg*4+0][kk] * wv;
      acc[1] += xs[rg*4+1][kk] * wv;
      acc[2] += xs[rg*4+2][kk] * wv;
      acc[3] += xs[rg*4+3][kk] * wv;
    }
    __syncthreads();
  }
  const float b1h = b1[h], w2h = W2[h];
  #pragma unroll
  for (int r = 0; r < 4; ++r) {
    float val = fmaxf(acc[r] + b1h, 0.f) * w2h;
    val = wave_sum(val);
    if (h == 0) e2out[row0 + rg*4 + r] = val;
  }
}

__global__ __launch_bounds__(256) void softmax_w_kernel(
    const float* __restrict__ e2in, float* __restrict__ w)
{
  __shared__ float redm[4];
  __shared__ float reds[4];
  const int b = blockIdx.x, t = threadIdx.x;
  const int lane = t & 63, wid = t >> 6;
  const float* row = e2in + (size_t)b*C_;
  float4 v = *(const float4*)&row[t*4];
  float m = fmaxf(fmaxf(v.x, v.y), fmaxf(v.z, v.w));
  m = wave_max(m);
  if (lane == 0) redm[wid] = m;
  __syncthreads();
  m = fmaxf(fmaxf(redm[0], redm[1]), fmaxf(redm[2], redm[3]));
  float e0 = expf(v.x - m), e1 = expf(v.y - m);
  float e2 = expf(v.z - m), e3 = expf(v.w - m);
  float s = e0 + e1 + e2 + e3;
  s = wave_sum(s);
  if (lane == 0) reds[wid] = s;
  __syncthreads();
  s = reds[0] + reds[1] + reds[2] + reds[3];
  const float inv = 1.0f / s;
  float4 o; o.x = e0*inv; o.y = e1*inv; o.z = e2*inv; o.w = e3*inv;
  *(float4*)&w[(size_t)b*C_ + t*4] = o;
}

// ---------------- final reduction, split over i ----------------
// fpart[s][b][d0..3] = gamma*sum_{i in s} u[b,i]*v[b,i,d] + sum_{i in s} w[b,i]*x[b,i,d]
__global__ __launch_bounds__(256) void final_part_kernel(
    const float* __restrict__ X, const float* __restrict__ V,
    const float* __restrict__ u, const float* __restrict__ w,
    const float* __restrict__ gamma, float* __restrict__ fpart)
{
  const int b = blockIdx.x, s = blockIdx.y;    // s: 0..63 -> i in [s*16, s*16+16)
  const int d0 = threadIdx.x * 4;
  const float* xb = X + (size_t)b*C_*D_;
  const float* vb = V + (size_t)b*C_*D_;
  const float* ub = u + (size_t)b*C_;
  const float* wb = w + (size_t)b*C_;
  float4 av = {0,0,0,0}, ax = {0,0,0,0};
  #pragma unroll
  for (int ii = 0; ii < 16; ++ii) {
    const int i = s*16 + ii;
    const float ui = ub[i], wi = wb[i];
    float4 vv = *(const float4*)&vb[(size_t)i*D_ + d0];
    float4 xv = *(const float4*)&xb[(size_t)i*D_ + d0];
    av.x += ui*vv.x; av.y += ui*vv.y; av.z += ui*vv.z; av.w += ui*vv.w;
    ax.x += wi*xv.x; ax.y += wi*xv.y; ax.z += wi*xv.z; ax.w += wi*xv.w;
  }
  const float g = gamma[0];
  float4 o;
  o.x = g*av.x + ax.x; o.y = g*av.y + ax.y;
  o.z = g*av.z + ax.z; o.w = g*av.w + ax.w;
  *(float4*)&fpart[((size_t)s*B_ + b)*D_ + d0] = o;
}

__global__ __launch_bounds__(256) void final_combine_kernel(
    const float* __restrict__ fpart, float* __restrict__ out)
{
  const int idx = blockIdx.x*256 + threadIdx.x;   // over B_*D_
  float s = 0.f;
  #pragma unroll 8
  for (int sp = 0; sp < 64; ++sp) s += fpart[(size_t)sp*B_*D_ + idx];
  out[idx] = s;
}

extern "C" void kernel_launch(void* const* d_in, const int* in_sizes, int n_in,
                              void* d_out, int out_size, void* d_ws, size_t ws_size,
                              hipStream_t stream) {
  (void)in_sizes; (void)n_in; (void)out_size;
  const float* x  = (const float*)d_in[0];
  const float* Wf = (const float*)d_in[1];
  const float* bf = (const float*)d_in[2];
  const float* Wg = (const float*)d_in[3];
  const float* bg = (const float*)d_in[4];
  const float* Wx = (const float*)d_in[5];
  const float* bx = (const float*)d_in[6];
  const float* W1 = (const float*)d_in[7];
  const float* b1 = (const float*)d_in[8];
  const float* W2 = (const float*)d_in[9];
  const float* gamma = (const float*)d_in[11];
  float* out = (float*)d_out;

  // workspace layout
  ushort* x_bf = (ushort*)d_ws;                  // 32 MB
  ushort* wtf  = x_bf + (size_t)M_*D_;           // 2 MB x3
  ushort* wtg  = wtf + (size_t)D_*D_;
  ushort* wtx  = wtg + (size_t)D_*D_;
  ushort* q_bf = wtx + (size_t)D_*D_;            // 32 MB
  ushort* k_bf = q_bf + (size_t)M_*D_;           // 32 MB
  float*  v    = (float*)(k_bf + (size_t)M_*D_); // 64 MB
  float*  e2b  = v + (size_t)M_*D_;              // 64 KB
  float*  wbuf = e2b + M_;                       // 64 KB
  float*  u    = wbuf + M_;                      // 64 KB
  float*  u_part = u + M_;                       // 4 MB (aliased as fpart later)
  float*  fpart  = u_part;                       // reuse: u_part dead after u_combine
  float*  E    = u_part + (size_t)64*B_*C_;
  const size_t base = (size_t)((char*)E - (char*)d_ws);
  const size_t ebytes = (size_t)C_*C_*sizeof(float);   // 4 MiB / batch
  int chunkB = (ws_size > base) ? (int)((ws_size - base) / ebytes) : 1;
  if (chunkB > B_) chunkB = B_;
  if (chunkB < 1) chunkB = 1;

  // bf16 conversions
  cvt_kernel<<<dim3((M_*D_/4 + 255)/256), 256, 0, stream>>>(x, x_bf, M_*D_/4);
  tconv_kernel<<<dim3(32,32), 256, 0, stream>>>(Wf, wtf);
  tconv_kernel<<<dim3(32,32), 256, 0, stream>>>(Wg, wtg);
  tconv_kernel<<<dim3(32,32), 256, 0, stream>>>(Wx, wtx);

  // projections (bf16 MFMA): q,k -> bf16, v -> f32
  mfma_nt_kernel<1><<<dim3(8,128,1), 256, 0, stream>>>(x_bf, wtf, bf, q_bf, 0,0,0);
  mfma_nt_kernel<1><<<dim3(8,128,1), 256, 0, stream>>>(x_bf, wtg, bg, k_bf, 0,0,0);
  mfma_nt_kernel<2><<<dim3(8,128,1), 256, 0, stream>>>(x_bf, wtx, bx, v,    0,0,0);

  // pooling weights
  pool_kernel<<<dim3(M_/16), 256, 0, stream>>>(x, W1, b1, W2, e2b);
  softmax_w_kernel<<<dim3(B_), 256, 0, stream>>>(e2b, wbuf);

  // energy (bf16 MFMA) + fused softmax/colsum, chunked over batch
  for (int b0 = 0; b0 < B_; b0 += chunkB) {
    const int nb = (B_ - b0 < chunkB) ? (B_ - b0) : chunkB;
    mfma_nt_kernel<0><<<dim3(8,8,nb), 256, 0, stream>>>(
        k_bf + (size_t)b0*C_*D_, q_bf + (size_t)b0*C_*D_, nullptr, E,
        (size_t)C_*D_, (size_t)C_*D_, (size_t)C_*C_);
    fused_sm_kernel<<<dim3(64,nb), 256, 0, stream>>>(E, wbuf, u_part, b0);
  }
  u_combine_kernel<<<dim3(M_/256), 256, 0, stream>>>(u_part, u);

  // final: split over i, then combine
  final_part_kernel<<<dim3(B_,64), 256, 0, stream>>>(x, v, u, wbuf, gamma, fpart);
  final_combine_kernel<<<dim3(M_/256), 256, 0, stream>>>(fpart, out);
}

// Round 4
// 360.739 us; speedup vs baseline: 7.8501x; 1.3752x over previous
//
#include <hip/hip_runtime.h>

#define B_ 16
#define C_ 1024
#define D_ 1024
#define H_ 64
#define M_ (B_*C_)   // 16384

typedef __attribute__((ext_vector_type(8))) short bf16x8;
typedef __attribute__((ext_vector_type(8))) unsigned short ushortx8;
typedef __attribute__((ext_vector_type(4))) float f32x4;

__device__ __forceinline__ float wave_max(float v){
  #pragma unroll
  for (int o = 32; o > 0; o >>= 1) v = fmaxf(v, __shfl_xor(v, o));
  return v;
}
__device__ __forceinline__ float wave_sum(float v){
  #pragma unroll
  for (int o = 32; o > 0; o >>= 1) v += __shfl_xor(v, o);
  return v;
}

// fp32 -> bf16 (RNE)
__device__ __forceinline__ ushort f2bf(float f){
  union { float f; unsigned u; } a; a.f = f;
  unsigned r = a.u + 0x7fff + ((a.u >> 16) & 1);
  return (ushort)(r >> 16);
}
__device__ __forceinline__ float bf2f(ushort h){
  union { unsigned u; float f; } a; a.u = ((unsigned)h) << 16; return a.f;
}

// async global->LDS, 16 B per lane; LDS dest is wave-uniform base + lane*16.
__device__ __forceinline__ void lds_cp16(const ushort* g, ushort* l){
  __builtin_amdgcn_global_load_lds(
      (const __attribute__((address_space(1))) void*)g,
      (__attribute__((address_space(3))) void*)l, 16, 0, 0);
}

// ---------------- conversion kernels ----------------

__global__ __launch_bounds__(256) void cvt_kernel(
    const float* __restrict__ in, ushort* __restrict__ out, int n4)
{
  int i = blockIdx.x*256 + threadIdx.x;
  if (i >= n4) return;
  float4 v = ((const float4*)in)[i];
  ushort4 o;
  o.x = f2bf(v.x); o.y = f2bf(v.y); o.z = f2bf(v.z); o.w = f2bf(v.w);
  ((ushort4*)out)[i] = o;
}

// Wt[n][k] = bf16(W[k][n]);  W: 1024x1024 row-major
__global__ __launch_bounds__(256) void tconv_kernel(
    const float* __restrict__ W, ushort* __restrict__ Wt)
{
  __shared__ float tile[32][33];
  const int t = threadIdx.x;
  const int tx = t & 31, ty = t >> 5;          // 32 x 8
  const int n0 = blockIdx.x*32, k0 = blockIdx.y*32;
  #pragma unroll
  for (int i = 0; i < 32; i += 8)
    tile[ty+i][tx] = W[(size_t)(k0+ty+i)*D_ + n0+tx];
  __syncthreads();
  #pragma unroll
  for (int i = 0; i < 32; i += 8)
    Wt[(size_t)(n0+ty+i)*D_ + k0+tx] = f2bf(tile[tx][ty+i]);
}

// W1t[n][k] = bf16(W1[k][n]);  W1: 1024x64
__global__ __launch_bounds__(256) void tconv64_kernel(
    const float* __restrict__ W1, ushort* __restrict__ W1t)
{
  __shared__ float tile[32][33];
  const int t = threadIdx.x;
  const int tx = t & 31, ty = t >> 5;
  const int n0 = blockIdx.x*32, k0 = blockIdx.y*32;
  #pragma unroll
  for (int i = 0; i < 32; i += 8)
    tile[ty+i][tx] = W1[(size_t)(k0+ty+i)*H_ + n0+tx];
  __syncthreads();
  #pragma unroll
  for (int i = 0; i < 32; i += 8)
    W1t[(size_t)(n0+ty+i)*D_ + k0+tx] = f2bf(tile[tx][ty+i]);
}

// ---------------- merged QKV projection: NT GEMM, N=3072 ----------------
// Out_seg[m][n] = relu(sum_k x[m][k]*Wt[seg*1024+n][k] + b_seg[n]) -> bf16
__global__ __launch_bounds__(256) void proj_kernel(
    const ushort* __restrict__ A, const ushort* __restrict__ Wt,
    const float* __restrict__ bf, const float* __restrict__ bg,
    const float* __restrict__ bx,
    ushort* __restrict__ q, ushort* __restrict__ k, ushort* __restrict__ v)
{
  __shared__ ushort As[128*32];
  __shared__ ushort Bs[128*32];
  const int t = threadIdx.x;
  const int wid = t >> 6, lane = t & 63;
  const int m0 = blockIdx.y * 128, n0 = blockIdx.x * 128;   // n0 in [0,3072)
  const int seg = n0 >> 10;                                  // 0:q 1:k 2:v
  const int nloc0 = n0 - (seg << 10);

  const int r = t >> 2;
  const int kc = (t & 3) * 8;
  const ushort* ga0 = A + (size_t)(m0 + r)*1024 + kc;
  const ushort* ga1 = ga0 + (size_t)64*1024;
  const ushort* gb0 = Wt + (size_t)(n0 + r)*1024 + kc;
  const ushort* gb1 = gb0 + (size_t)64*1024;
  ushort* lA = As + wid*512;
  ushort* lB = Bs + wid*512;

  const int quad = lane >> 4, l16 = lane & 15;
  const int wm = wid >> 1, wn = wid & 1;
  const int am0 = (wm*64 + l16)*32 + quad*8;
  const int bn0 = (wn*64 + l16)*32 + quad*8;

  f32x4 acc[4][4] = {};

  for (int k0 = 0; k0 < 1024; k0 += 32) {
    lds_cp16(ga0, lA); lds_cp16(ga1, lA + 2048);
    lds_cp16(gb0, lB); lds_cp16(gb1, lB + 2048);
    ga0 += 32; ga1 += 32; gb0 += 32; gb1 += 32;
    __syncthreads();
    bf16x8 af[4], bfr[4];
    #pragma unroll
    for (int i = 0; i < 4; ++i) {
      af[i]  = *(const bf16x8*)&As[am0 + i*512];
      bfr[i] = *(const bf16x8*)&Bs[bn0 + i*512];
    }
    #pragma unroll
    for (int mt = 0; mt < 4; ++mt)
      #pragma unroll
      for (int nt = 0; nt < 4; ++nt)
        acc[mt][nt] = __builtin_amdgcn_mfma_f32_16x16x32_bf16(
            af[mt], bfr[nt], acc[mt][nt], 0, 0, 0);
    __syncthreads();
  }

  const float* bp = (seg == 0) ? bf : (seg == 1) ? bg : bx;
  ushort* op      = (seg == 0) ? q  : (seg == 1) ? k  : v;
  const int gm_base = m0 + wm*64 + quad*4;
  const int gn_base = nloc0 + wn*64 + l16;
  float bv[4];
  #pragma unroll
  for (int nt = 0; nt < 4; ++nt) bv[nt] = bp[gn_base + nt*16];
  #pragma unroll
  for (int mt = 0; mt < 4; ++mt)
    #pragma unroll
    for (int rr = 0; rr < 4; ++rr) {
      const size_t rowoff = (size_t)(gm_base + mt*16 + rr) * 1024;
      #pragma unroll
      for (int nt = 0; nt < 4; ++nt)
        op[rowoff + gn_base + nt*16] =
            f2bf(fmaxf(acc[mt][nt][rr] + bv[nt], 0.f));
    }
}

// ---------------- energy: NT GEMM, bf16 out ----------------
// E'[bz][j][i] = bf16(sum_d k[j,d]*q[i,d])
__global__ __launch_bounds__(256) void energy_kernel(
    const ushort* __restrict__ Km, const ushort* __restrict__ Qm,
    ushort* __restrict__ E)
{
  __shared__ ushort As[128*32];
  __shared__ ushort Bs[128*32];
  const int t = threadIdx.x;
  const int wid = t >> 6, lane = t & 63;
  const int m0 = blockIdx.y * 128, n0 = blockIdx.x * 128;
  const ushort* Ab = Km + (size_t)blockIdx.z * C_ * D_;
  const ushort* Bb = Qm + (size_t)blockIdx.z * C_ * D_;

  const int r = t >> 2;
  const int kc = (t & 3) * 8;
  const ushort* ga0 = Ab + (size_t)(m0 + r)*1024 + kc;
  const ushort* ga1 = ga0 + (size_t)64*1024;
  const ushort* gb0 = Bb + (size_t)(n0 + r)*1024 + kc;
  const ushort* gb1 = gb0 + (size_t)64*1024;
  ushort* lA = As + wid*512;
  ushort* lB = Bs + wid*512;

  const int quad = lane >> 4, l16 = lane & 15;
  const int wm = wid >> 1, wn = wid & 1;
  const int am0 = (wm*64 + l16)*32 + quad*8;
  const int bn0 = (wn*64 + l16)*32 + quad*8;

  f32x4 acc[4][4] = {};

  for (int k0 = 0; k0 < 1024; k0 += 32) {
    lds_cp16(ga0, lA); lds_cp16(ga1, lA + 2048);
    lds_cp16(gb0, lB); lds_cp16(gb1, lB + 2048);
    ga0 += 32; ga1 += 32; gb0 += 32; gb1 += 32;
    __syncthreads();
    bf16x8 af[4], bfr[4];
    #pragma unroll
    for (int i = 0; i < 4; ++i) {
      af[i]  = *(const bf16x8*)&As[am0 + i*512];
      bfr[i] = *(const bf16x8*)&Bs[bn0 + i*512];
    }
    #pragma unroll
    for (int mt = 0; mt < 4; ++mt)
      #pragma unroll
      for (int nt = 0; nt < 4; ++nt)
        acc[mt][nt] = __builtin_amdgcn_mfma_f32_16x16x32_bf16(
            af[mt], bfr[nt], acc[mt][nt], 0, 0, 0);
    __syncthreads();
  }

  ushort* O = E + (size_t)blockIdx.z * C_ * C_;
  const int gm_base = m0 + wm*64 + quad*4;
  const int gn_base = n0 + wn*64 + l16;
  #pragma unroll
  for (int mt = 0; mt < 4; ++mt)
    #pragma unroll
    for (int rr = 0; rr < 4; ++rr) {
      const size_t rowoff = (size_t)(gm_base + mt*16 + rr) * 1024;
      #pragma unroll
      for (int nt = 0; nt < 4; ++nt)
        O[rowoff + gn_base + nt*16] = f2bf(acc[mt][nt][rr]);
    }
}

// ---------------- pooling MLP via MFMA ----------------
// e2[m] = sum_n relu(sum_k x[m][k]*W1t[n][k] + b1[n]) * W2[n],  n<64
__global__ __launch_bounds__(256) void pool_mfma_kernel(
    const ushort* __restrict__ A, const ushort* __restrict__ Bt,
    const float* __restrict__ b1, const float* __restrict__ W2,
    float* __restrict__ e2out)
{
  __shared__ ushort As[128*32];
  __shared__ ushort Bs[64*32];
  const int t = threadIdx.x;
  const int wid = t >> 6, lane = t & 63;
  const int m0 = blockIdx.x * 128;

  const int r = t >> 2;
  const int kc = (t & 3) * 8;
  const ushort* ga0 = A + (size_t)(m0 + r)*1024 + kc;
  const ushort* ga1 = ga0 + (size_t)64*1024;
  const ushort* gb0 = Bt + (size_t)r*1024 + kc;
  ushort* lA = As + wid*512;
  ushort* lB = Bs + wid*512;

  const int quad = lane >> 4, l16 = lane & 15;
  const int am0 = (wid*32 + l16)*32 + quad*8;
  const int bn0 = l16*32 + quad*8;

  f32x4 acc[2][4] = {};

  for (int k0 = 0; k0 < 1024; k0 += 32) {
    lds_cp16(ga0, lA); lds_cp16(ga1, lA + 2048);
    lds_cp16(gb0, lB);
    ga0 += 32; ga1 += 32; gb0 += 32;
    __syncthreads();
    bf16x8 af[2], bfr[4];
    #pragma unroll
    for (int i = 0; i < 2; ++i) af[i] = *(const bf16x8*)&As[am0 + i*512];
    #pragma unroll
    for (int i = 0; i < 4; ++i) bfr[i] = *(const bf16x8*)&Bs[bn0 + i*512];
    #pragma unroll
    for (int mt = 0; mt < 2; ++mt)
      #pragma unroll
      for (int nt = 0; nt < 4; ++nt)
        acc[mt][nt] = __builtin_amdgcn_mfma_f32_16x16x32_bf16(
            af[mt], bfr[nt], acc[mt][nt], 0, 0, 0);
    __syncthreads();
  }

  float b1v[4], w2v[4];
  #pragma unroll
  for (int nt = 0; nt < 4; ++nt) {
    b1v[nt] = b1[nt*16 + l16];
    w2v[nt] = W2[nt*16 + l16];
  }
  #pragma unroll
  for (int mt = 0; mt < 2; ++mt)
    #pragma unroll
    for (int rr = 0; rr < 4; ++rr) {
      float h = 0.f;
      #pragma unroll
      for (int nt = 0; nt < 4; ++nt)
        h += fmaxf(acc[mt][nt][rr] + b1v[nt], 0.f) * w2v[nt];
      #pragma unroll
      for (int o = 1; o < 16; o <<= 1) h += __shfl_xor(h, o);
      if (l16 == 0)
        e2out[m0 + wid*32 + mt*16 + quad*4 + rr] = h;
    }
}

// ---------------- fused row-softmax + weighted column-sum (bf16 E) --------

__global__ __launch_bounds__(256) void fused_sm_kernel(
    const ushort* __restrict__ E, const float* __restrict__ w,
    float* __restrict__ u_part)
{
  __shared__ float ul[4][1024];
  const int b = blockIdx.y;
  const int strip = blockIdx.x;       // 0..63
  const int t = threadIdx.x, wv = t >> 6, lane = t & 63;
  const ushort* Eb = E + (size_t)b*C_*C_;
  const float* wb = w + (size_t)b*C_;
  float acc[2][8] = {};               // i = c*512 + lane*8 + k
  #pragma unroll
  for (int rj = 0; rj < 4; ++rj) {
    const int j = strip*16 + wv*4 + rj;
    const ushort* row = Eb + (size_t)j*C_;
    float vv[2][8];
    float m = -1e30f;
    #pragma unroll
    for (int c = 0; c < 2; ++c) {
      ushortx8 h = *(const ushortx8*)&row[c*512 + lane*8];
      #pragma unroll
      for (int kk = 0; kk < 8; ++kk) {
        vv[c][kk] = bf2f(h[kk]);
        m = fmaxf(m, vv[c][kk]);
      }
    }
    m = wave_max(m);
    float e[2][8];
    float s = 0.f;
    #pragma unroll
    for (int c = 0; c < 2; ++c)
      #pragma unroll
      for (int kk = 0; kk < 8; ++kk) {
        e[c][kk] = expf(vv[c][kk] - m);
        s += e[c][kk];
      }
    s = wave_sum(s);
    const float sc = wb[j] / s;
    #pragma unroll
    for (int c = 0; c < 2; ++c)
      #pragma unroll
      for (int kk = 0; kk < 8; ++kk) acc[c][kk] += sc * e[c][kk];
  }
  #pragma unroll
  for (int c = 0; c < 2; ++c)
    #pragma unroll
    for (int k4 = 0; k4 < 2; ++k4) {
      float4 o;
      o.x = acc[c][k4*4+0]; o.y = acc[c][k4*4+1];
      o.z = acc[c][k4*4+2]; o.w = acc[c][k4*4+3];
      *(float4*)&ul[wv][c*512 + lane*8 + k4*4] = o;
    }
  __syncthreads();
  float4 r0 = *(float4*)&ul[0][t*4];
  float4 r1 = *(float4*)&ul[1][t*4];
  float4 r2 = *(float4*)&ul[2][t*4];
  float4 r3 = *(float4*)&ul[3][t*4];
  float4 o;
  o.x = r0.x+r1.x+r2.x+r3.x; o.y = r0.y+r1.y+r2.y+r3.y;
  o.z = r0.z+r1.z+r2.z+r3.z; o.w = r0.w+r1.w+r2.w+r3.w;
  *(float4*)&u_part[((size_t)strip*B_ + b)*C_ + t*4] = o;
}

__global__ __launch_bounds__(256) void u_combine_kernel(
    const float* __restrict__ u_part, float* __restrict__ u)
{
  const int idx = blockIdx.x*256 + threadIdx.x;   // over B_*C_
  float s = 0.f;
  #pragma unroll 8
  for (int sp = 0; sp < 64; ++sp) s += u_part[(size_t)sp*B_*C_ + idx];
  u[idx] = s;
}

// ---------------- pooling softmax ----------------

__global__ __launch_bounds__(256) void softmax_w_kernel(
    const float* __restrict__ e2in, float* __restrict__ w)
{
  __shared__ float redm[4];
  __shared__ float reds[4];
  const int b = blockIdx.x, t = threadIdx.x;
  const int lane = t & 63, wid = t >> 6;
  const float* row = e2in + (size_t)b*C_;
  float4 v = *(const float4*)&row[t*4];
  float m = fmaxf(fmaxf(v.x, v.y), fmaxf(v.z, v.w));
  m = wave_max(m);
  if (lane == 0) redm[wid] = m;
  __syncthreads();
  m = fmaxf(fmaxf(redm[0], redm[1]), fmaxf(redm[2], redm[3]));
  float e0 = expf(v.x - m), e1 = expf(v.y - m);
  float e2 = expf(v.z - m), e3 = expf(v.w - m);
  float s = e0 + e1 + e2 + e3;
  s = wave_sum(s);
  if (lane == 0) reds[wid] = s;
  __syncthreads();
  s = reds[0] + reds[1] + reds[2] + reds[3];
  const float inv = 1.0f / s;
  float4 o; o.x = e0*inv; o.y = e1*inv; o.z = e2*inv; o.w = e3*inv;
  *(float4*)&w[(size_t)b*C_ + t*4] = o;
}

// ---------------- final reduction, split over i (bf16 x, v) ----------------

__global__ __launch_bounds__(256) void final_part_kernel(
    const ushort* __restrict__ X, const ushort* __restrict__ V,
    const float* __restrict__ u, const float* __restrict__ w,
    const float* __restrict__ gamma, float* __restrict__ fpart)
{
  const int b = blockIdx.x, s = blockIdx.y;    // i in [s*16, s*16+16)
  const int d0 = threadIdx.x * 4;
  const ushort* xb = X + (size_t)b*C_*D_;
  const ushort* vb = V + (size_t)b*C_*D_;
  const float* ub = u + (size_t)b*C_;
  const float* wb = w + (size_t)b*C_;
  float4 av = {0,0,0,0}, ax = {0,0,0,0};
  #pragma unroll
  for (int ii = 0; ii < 16; ++ii) {
    const int i = s*16 + ii;
    const float ui = ub[i], wi = wb[i];
    ushort4 vv = *(const ushort4*)&vb[(size_t)i*D_ + d0];
    ushort4 xv = *(const ushort4*)&xb[(size_t)i*D_ + d0];
    av.x += ui*bf2f(vv.x); av.y += ui*bf2f(vv.y);
    av.z += ui*bf2f(vv.z); av.w += ui*bf2f(vv.w);
    ax.x += wi*bf2f(xv.x); ax.y += wi*bf2f(xv.y);
    ax.z += wi*bf2f(xv.z); ax.w += wi*bf2f(xv.w);
  }
  const float g = gamma[0];
  float4 o;
  o.x = g*av.x + ax.x; o.y = g*av.y + ax.y;
  o.z = g*av.z + ax.z; o.w = g*av.w + ax.w;
  *(float4*)&fpart[((size_t)s*B_ + b)*D_ + d0] = o;
}

__global__ __launch_bounds__(256) void final_combine_kernel(
    const float* __restrict__ fpart, float* __restrict__ out)
{
  const int idx = blockIdx.x*256 + threadIdx.x;   // over B_*D_
  float s = 0.f;
  #pragma unroll 8
  for (int sp = 0; sp < 64; ++sp) s += fpart[(size_t)sp*B_*D_ + idx];
  out[idx] = s;
}

extern "C" void kernel_launch(void* const* d_in, const int* in_sizes, int n_in,
                              void* d_out, int out_size, void* d_ws, size_t ws_size,
                              hipStream_t stream) {
  (void)in_sizes; (void)n_in; (void)out_size; (void)ws_size;
  const float* x  = (const float*)d_in[0];
  const float* Wf = (const float*)d_in[1];
  const float* bf = (const float*)d_in[2];
  const float* Wg = (const float*)d_in[3];
  const float* bg = (const float*)d_in[4];
  const float* Wx = (const float*)d_in[5];
  const float* bx = (const float*)d_in[6];
  const float* W1 = (const float*)d_in[7];
  const float* b1 = (const float*)d_in[8];
  const float* W2 = (const float*)d_in[9];
  const float* gamma = (const float*)d_in[11];
  float* out = (float*)d_out;

  // workspace layout (~170 MB total)
  ushort* x_bf = (ushort*)d_ws;                  // 32 MB
  ushort* wt   = x_bf + (size_t)M_*D_;           // 6 MB (Wf^T|Wg^T|Wx^T contiguous)
  ushort* w1t  = wt + (size_t)3*D_*D_;           // 128 KB
  ushort* q_bf = w1t + (size_t)H_*D_;            // 32 MB
  ushort* k_bf = q_bf + (size_t)M_*D_;           // 32 MB
  ushort* v_bf = k_bf + (size_t)M_*D_;           // 32 MB
  ushort* E    = v_bf + (size_t)M_*D_;           // 32 MB (bf16, all batches)
  float*  e2b  = (float*)(E + (size_t)B_*C_*C_); // 64 KB
  float*  wbuf = e2b + M_;                       // 64 KB
  float*  u    = wbuf + M_;                      // 64 KB
  float*  u_part = u + M_;                       // 4 MB
  float*  fpart  = u_part;                       // alias: u_part dead after u_combine

  // bf16 conversions
  cvt_kernel<<<dim3((M_*D_/4 + 255)/256), 256, 0, stream>>>(x, x_bf, M_*D_/4);
  tconv_kernel<<<dim3(32,32), 256, 0, stream>>>(Wf, wt);
  tconv_kernel<<<dim3(32,32), 256, 0, stream>>>(Wg, wt + (size_t)D_*D_);
  tconv_kernel<<<dim3(32,32), 256, 0, stream>>>(Wx, wt + (size_t)2*D_*D_);
  tconv64_kernel<<<dim3(2,32), 256, 0, stream>>>(W1, w1t);

  // merged q/k/v projection (bf16 MFMA, N=3072)
  proj_kernel<<<dim3(24,128), 256, 0, stream>>>(x_bf, wt, bf, bg, bx,
                                                q_bf, k_bf, v_bf);

  // pooling weights (MFMA MLP + softmax)
  pool_mfma_kernel<<<dim3(M_/128), 256, 0, stream>>>(x_bf, w1t, b1, W2, e2b);
  softmax_w_kernel<<<dim3(B_), 256, 0, stream>>>(e2b, wbuf);

  // energy (bf16 MFMA, bf16 out) + fused softmax/colsum
  energy_kernel<<<dim3(8,8,B_), 256, 0, stream>>>(k_bf, q_bf, E);
  fused_sm_kernel<<<dim3(64,B_), 256, 0, stream>>>(E, wbuf, u_part);
  u_combine_kernel<<<dim3(M_/256), 256, 0, stream>>>(u_part, u);

  // final: split over i, then combine
  final_part_kernel<<<dim3(B_,64), 256, 0, stream>>>(x_bf, v_bf, u, wbuf, gamma, fpart);
  final_combine_kernel<<<dim3(M_/256), 256, 0, stream>>>(fpart, out);
}

// Round 5
// 360.278 us; speedup vs baseline: 7.8602x; 1.0013x over previous
//
#include <hip/hip_runtime.h>

#define B_ 16
#define C_ 1024
#define D_ 1024
#define H_ 64
#define M_ (B_*C_)   // 16384

typedef __attribute__((ext_vector_type(8))) short bf16x8;
typedef __attribute__((ext_vector_type(8))) unsigned short ushortx8;
typedef __attribute__((ext_vector_type(4))) float f32x4;

__device__ __forceinline__ float wave_max(float v){
  #pragma unroll
  for (int o = 32; o > 0; o >>= 1) v = fmaxf(v, __shfl_xor(v, o));
  return v;
}
__device__ __forceinline__ float wave_sum(float v){
  #pragma unroll
  for (int o = 32; o > 0; o >>= 1) v += __shfl_xor(v, o);
  return v;
}

// fp32 -> bf16 (RNE)
__device__ __forceinline__ ushort f2bf(float f){
  union { float f; unsigned u; } a; a.f = f;
  unsigned r = a.u + 0x7fff + ((a.u >> 16) & 1);
  return (ushort)(r >> 16);
}
__device__ __forceinline__ float bf2f(ushort h){
  union { unsigned u; float f; } a; a.u = ((unsigned)h) << 16; return a.f;
}

// async global->LDS, 16 B per lane; LDS dest is wave-uniform base + lane*16.
__device__ __forceinline__ void lds_cp16(const ushort* g, ushort* l){
  __builtin_amdgcn_global_load_lds(
      (const __attribute__((address_space(1))) void*)g,
      (__attribute__((address_space(3))) void*)l, 16, 0, 0);
}

// k-chunk swizzle: LDS[row][slot] holds global chunk slot ^ fsw(row).
// Makes quad-strided ds_read_b128 fragment reads uniform 2-way (free) instead
// of 8-way (2.9x). Invariant under row+16, so one constant per lane suffices.
__device__ __forceinline__ int fsw(int row){
  return (row & 3) ^ ((row >> 2) & 3);
}

// ---------------- conversion kernels ----------------

__global__ __launch_bounds__(256) void cvt_kernel(
    const float* __restrict__ in, ushort* __restrict__ out, int n4)
{
  int i = blockIdx.x*256 + threadIdx.x;
  if (i >= n4) return;
  float4 v = ((const float4*)in)[i];
  ushort4 o;
  o.x = f2bf(v.x); o.y = f2bf(v.y); o.z = f2bf(v.z); o.w = f2bf(v.w);
  ((ushort4*)out)[i] = o;
}

// Wt[z][n][k] = bf16(W_z[k][n]);  W_z: 1024x1024 row-major, z in {f,g,x}
__global__ __launch_bounds__(256) void tconv3_kernel(
    const float* __restrict__ Wf, const float* __restrict__ Wg,
    const float* __restrict__ Wx, ushort* __restrict__ Wt)
{
  __shared__ float tile[32][33];
  const int z = blockIdx.z;
  const float* W = (z == 0) ? Wf : (z == 1) ? Wg : Wx;
  ushort* Out = Wt + (size_t)z*D_*D_;
  const int t = threadIdx.x;
  const int tx = t & 31, ty = t >> 5;          // 32 x 8
  const int n0 = blockIdx.x*32, k0 = blockIdx.y*32;
  #pragma unroll
  for (int i = 0; i < 32; i += 8)
    tile[ty+i][tx] = W[(size_t)(k0+ty+i)*D_ + n0+tx];
  __syncthreads();
  #pragma unroll
  for (int i = 0; i < 32; i += 8)
    Out[(size_t)(n0+ty+i)*D_ + k0+tx] = f2bf(tile[tx][ty+i]);
}

// W1t[n][k] = bf16(W1[k][n]);  W1: 1024x64
__global__ __launch_bounds__(256) void tconv64_kernel(
    const float* __restrict__ W1, ushort* __restrict__ W1t)
{
  __shared__ float tile[32][33];
  const int t = threadIdx.x;
  const int tx = t & 31, ty = t >> 5;
  const int n0 = blockIdx.x*32, k0 = blockIdx.y*32;
  #pragma unroll
  for (int i = 0; i < 32; i += 8)
    tile[ty+i][tx] = W1[(size_t)(k0+ty+i)*H_ + n0+tx];
  __syncthreads();
  #pragma unroll
  for (int i = 0; i < 32; i += 8)
    W1t[(size_t)(n0+ty+i)*D_ + k0+tx] = f2bf(tile[tx][ty+i]);
}

// ---------------- merged QKV projection: NT GEMM, N=3072 ----------------
__global__ __launch_bounds__(256) void proj_kernel(
    const ushort* __restrict__ A, const ushort* __restrict__ Wt,
    const float* __restrict__ bf, const float* __restrict__ bg,
    const float* __restrict__ bx,
    ushort* __restrict__ q, ushort* __restrict__ k, ushort* __restrict__ v)
{
  __shared__ ushort As[128*32];
  __shared__ ushort Bs[128*32];
  const int t = threadIdx.x;
  const int wid = t >> 6, lane = t & 63;
  const int m0 = blockIdx.y * 128, n0 = blockIdx.x * 128;   // n0 in [0,3072)
  const int seg = n0 >> 10;                                  // 0:q 1:k 2:v
  const int nloc0 = n0 - (seg << 10);

  const int r = t >> 2;
  const int kc = ((t & 3) ^ fsw(r)) * 8;       // swizzled source chunk
  const ushort* ga0 = A + (size_t)(m0 + r)*1024 + kc;
  const ushort* ga1 = ga0 + (size_t)64*1024;
  const ushort* gb0 = Wt + (size_t)(n0 + r)*1024 + kc;
  const ushort* gb1 = gb0 + (size_t)64*1024;
  ushort* lA = As + wid*512;
  ushort* lB = Bs + wid*512;

  const int quad = lane >> 4, l16 = lane & 15;
  const int wm = wid >> 1, wn = wid & 1;
  const int fr = fsw(l16);
  const int am0 = (wm*64 + l16)*32 + ((quad ^ fr)*8);
  const int bn0 = (wn*64 + l16)*32 + ((quad ^ fr)*8);

  f32x4 acc[4][4] = {};

  for (int k0 = 0; k0 < 1024; k0 += 32) {
    lds_cp16(ga0, lA); lds_cp16(ga1, lA + 2048);
    lds_cp16(gb0, lB); lds_cp16(gb1, lB + 2048);
    ga0 += 32; ga1 += 32; gb0 += 32; gb1 += 32;
    __syncthreads();
    bf16x8 af[4], bfr[4];
    #pragma unroll
    for (int i = 0; i < 4; ++i) {
      af[i]  = *(const bf16x8*)&As[am0 + i*512];
      bfr[i] = *(const bf16x8*)&Bs[bn0 + i*512];
    }
    #pragma unroll
    for (int mt = 0; mt < 4; ++mt)
      #pragma unroll
      for (int nt = 0; nt < 4; ++nt)
        acc[mt][nt] = __builtin_amdgcn_mfma_f32_16x16x32_bf16(
            af[mt], bfr[nt], acc[mt][nt], 0, 0, 0);
    __syncthreads();
  }

  const float* bp = (seg == 0) ? bf : (seg == 1) ? bg : bx;
  ushort* op      = (seg == 0) ? q  : (seg == 1) ? k  : v;
  const int gm_base = m0 + wm*64 + quad*4;
  const int gn_base = nloc0 + wn*64 + l16;
  float bv[4];
  #pragma unroll
  for (int nt = 0; nt < 4; ++nt) bv[nt] = bp[gn_base + nt*16];
  #pragma unroll
  for (int mt = 0; mt < 4; ++mt)
    #pragma unroll
    for (int rr = 0; rr < 4; ++rr) {
      const size_t rowoff = (size_t)(gm_base + mt*16 + rr) * 1024;
      #pragma unroll
      for (int nt = 0; nt < 4; ++nt)
        op[rowoff + gn_base + nt*16] =
            f2bf(fmaxf(acc[mt][nt][rr] + bv[nt], 0.f));
    }
}

// ---------------- energy: NT GEMM, bf16 out ----------------
__global__ __launch_bounds__(256) void energy_kernel(
    const ushort* __restrict__ Km, const ushort* __restrict__ Qm,
    ushort* __restrict__ E)
{
  __shared__ ushort As[128*32];
  __shared__ ushort Bs[128*32];
  const int t = threadIdx.x;
  const int wid = t >> 6, lane = t & 63;
  const int m0 = blockIdx.y * 128, n0 = blockIdx.x * 128;
  const ushort* Ab = Km + (size_t)blockIdx.z * C_ * D_;
  const ushort* Bb = Qm + (size_t)blockIdx.z * C_ * D_;

  const int r = t >> 2;
  const int kc = ((t & 3) ^ fsw(r)) * 8;
  const ushort* ga0 = Ab + (size_t)(m0 + r)*1024 + kc;
  const ushort* ga1 = ga0 + (size_t)64*1024;
  const ushort* gb0 = Bb + (size_t)(n0 + r)*1024 + kc;
  const ushort* gb1 = gb0 + (size_t)64*1024;
  ushort* lA = As + wid*512;
  ushort* lB = Bs + wid*512;

  const int quad = lane >> 4, l16 = lane & 15;
  const int wm = wid >> 1, wn = wid & 1;
  const int fr = fsw(l16);
  const int am0 = (wm*64 + l16)*32 + ((quad ^ fr)*8);
  const int bn0 = (wn*64 + l16)*32 + ((quad ^ fr)*8);

  f32x4 acc[4][4] = {};

  for (int k0 = 0; k0 < 1024; k0 += 32) {
    lds_cp16(ga0, lA); lds_cp16(ga1, lA + 2048);
    lds_cp16(gb0, lB); lds_cp16(gb1, lB + 2048);
    ga0 += 32; ga1 += 32; gb0 += 32; gb1 += 32;
    __syncthreads();
    bf16x8 af[4], bfr[4];
    #pragma unroll
    for (int i = 0; i < 4; ++i) {
      af[i]  = *(const bf16x8*)&As[am0 + i*512];
      bfr[i] = *(const bf16x8*)&Bs[bn0 + i*512];
    }
    #pragma unroll
    for (int mt = 0; mt < 4; ++mt)
      #pragma unroll
      for (int nt = 0; nt < 4; ++nt)
        acc[mt][nt] = __builtin_amdgcn_mfma_f32_16x16x32_bf16(
            af[mt], bfr[nt], acc[mt][nt], 0, 0, 0);
    __syncthreads();
  }

  ushort* O = E + (size_t)blockIdx.z * C_ * C_;
  const int gm_base = m0 + wm*64 + quad*4;
  const int gn_base = n0 + wn*64 + l16;
  #pragma unroll
  for (int mt = 0; mt < 4; ++mt)
    #pragma unroll
    for (int rr = 0; rr < 4; ++rr) {
      const size_t rowoff = (size_t)(gm_base + mt*16 + rr) * 1024;
      #pragma unroll
      for (int nt = 0; nt < 4; ++nt)
        O[rowoff + gn_base + nt*16] = f2bf(acc[mt][nt][rr]);
    }
}

// ---------------- pooling MLP via MFMA ----------------
__global__ __launch_bounds__(256) void pool_mfma_kernel(
    const ushort* __restrict__ A, const ushort* __restrict__ Bt,
    const float* __restrict__ b1, const float* __restrict__ W2,
    float* __restrict__ e2out)
{
  __shared__ ushort As[128*32];
  __shared__ ushort Bs[64*32];
  const int t = threadIdx.x;
  const int wid = t >> 6, lane = t & 63;
  const int m0 = blockIdx.x * 128;

  const int r = t >> 2;
  const int kc = ((t & 3) ^ fsw(r)) * 8;
  const ushort* ga0 = A + (size_t)(m0 + r)*1024 + kc;
  const ushort* ga1 = ga0 + (size_t)64*1024;
  const ushort* gb0 = Bt + (size_t)r*1024 + kc;
  ushort* lA = As + wid*512;
  ushort* lB = Bs + wid*512;

  const int quad = lane >> 4, l16 = lane & 15;
  const int fr = fsw(l16);
  const int am0 = (wid*32 + l16)*32 + ((quad ^ fr)*8);
  const int bn0 = l16*32 + ((quad ^ fr)*8);

  f32x4 acc[2][4] = {};

  for (int k0 = 0; k0 < 1024; k0 += 32) {
    lds_cp16(ga0, lA); lds_cp16(ga1, lA + 2048);
    lds_cp16(gb0, lB);
    ga0 += 32; ga1 += 32; gb0 += 32;
    __syncthreads();
    bf16x8 af[2], bfr[4];
    #pragma unroll
    for (int i = 0; i < 2; ++i) af[i] = *(const bf16x8*)&As[am0 + i*512];
    #pragma unroll
    for (int i = 0; i < 4; ++i) bfr[i] = *(const bf16x8*)&Bs[bn0 + i*512];
    #pragma unroll
    for (int mt = 0; mt < 2; ++mt)
      #pragma unroll
      for (int nt = 0; nt < 4; ++nt)
        acc[mt][nt] = __builtin_amdgcn_mfma_f32_16x16x32_bf16(
            af[mt], bfr[nt], acc[mt][nt], 0, 0, 0);
    __syncthreads();
  }

  float b1v[4], w2v[4];
  #pragma unroll
  for (int nt = 0; nt < 4; ++nt) {
    b1v[nt] = b1[nt*16 + l16];
    w2v[nt] = W2[nt*16 + l16];
  }
  #pragma unroll
  for (int mt = 0; mt < 2; ++mt)
    #pragma unroll
    for (int rr = 0; rr < 4; ++rr) {
      float h = 0.f;
      #pragma unroll
      for (int nt = 0; nt < 4; ++nt)
        h += fmaxf(acc[mt][nt][rr] + b1v[nt], 0.f) * w2v[nt];
      #pragma unroll
      for (int o = 1; o < 16; o <<= 1) h += __shfl_xor(h, o);
      if (l16 == 0)
        e2out[m0 + wid*32 + mt*16 + quad*4 + rr] = h;
    }
}

// ---------------- fused row-softmax + weighted column-sum (bf16 E) --------

__global__ __launch_bounds__(256) void fused_sm_kernel(
    const ushort* __restrict__ E, const float* __restrict__ w,
    float* __restrict__ u_part)
{
  __shared__ float ul[4][1024];
  const int b = blockIdx.y;
  const int strip = blockIdx.x;       // 0..63
  const int t = threadIdx.x, wv = t >> 6, lane = t & 63;
  const ushort* Eb = E + (size_t)b*C_*C_;
  const float* wb = w + (size_t)b*C_;
  float acc[2][8] = {};               // i = c*512 + lane*8 + k
  #pragma unroll
  for (int rj = 0; rj < 4; ++rj) {
    const int j = strip*16 + wv*4 + rj;
    const ushort* row = Eb + (size_t)j*C_;
    float vv[2][8];
    float m = -1e30f;
    #pragma unroll
    for (int c = 0; c < 2; ++c) {
      ushortx8 h = *(const ushortx8*)&row[c*512 + lane*8];
      #pragma unroll
      for (int kk = 0; kk < 8; ++kk) {
        vv[c][kk] = bf2f(h[kk]);
        m = fmaxf(m, vv[c][kk]);
      }
    }
    m = wave_max(m);
    float e[2][8];
    float s = 0.f;
    #pragma unroll
    for (int c = 0; c < 2; ++c)
      #pragma unroll
      for (int kk = 0; kk < 8; ++kk) {
        e[c][kk] = expf(vv[c][kk] - m);
        s += e[c][kk];
      }
    s = wave_sum(s);
    const float sc = wb[j] / s;
    #pragma unroll
    for (int c = 0; c < 2; ++c)
      #pragma unroll
      for (int kk = 0; kk < 8; ++kk) acc[c][kk] += sc * e[c][kk];
  }
  #pragma unroll
  for (int c = 0; c < 2; ++c)
    #pragma unroll
    for (int k4 = 0; k4 < 2; ++k4) {
      float4 o;
      o.x = acc[c][k4*4+0]; o.y = acc[c][k4*4+1];
      o.z = acc[c][k4*4+2]; o.w = acc[c][k4*4+3];
      *(float4*)&ul[wv][c*512 + lane*8 + k4*4] = o;
    }
  __syncthreads();
  float4 r0 = *(float4*)&ul[0][t*4];
  float4 r1 = *(float4*)&ul[1][t*4];
  float4 r2 = *(float4*)&ul[2][t*4];
  float4 r3 = *(float4*)&ul[3][t*4];
  float4 o;
  o.x = r0.x+r1.x+r2.x+r3.x; o.y = r0.y+r1.y+r2.y+r3.y;
  o.z = r0.z+r1.z+r2.z+r3.z; o.w = r0.w+r1.w+r2.w+r3.w;
  *(float4*)&u_part[((size_t)strip*B_ + b)*C_ + t*4] = o;
}

__global__ __launch_bounds__(256) void u_combine_kernel(
    const float* __restrict__ u_part, float* __restrict__ u)
{
  const int idx = blockIdx.x*256 + threadIdx.x;   // over B_*C_
  float s = 0.f;
  #pragma unroll 8
  for (int sp = 0; sp < 64; ++sp) s += u_part[(size_t)sp*B_*C_ + idx];
  u[idx] = s;
}

// ---------------- pooling softmax ----------------

__global__ __launch_bounds__(256) void softmax_w_kernel(
    const float* __restrict__ e2in, float* __restrict__ w)
{
  __shared__ float redm[4];
  __shared__ float reds[4];
  const int b = blockIdx.x, t = threadIdx.x;
  const int lane = t & 63, wid = t >> 6;
  const float* row = e2in + (size_t)b*C_;
  float4 v = *(const float4*)&row[t*4];
  float m = fmaxf(fmaxf(v.x, v.y), fmaxf(v.z, v.w));
  m = wave_max(m);
  if (lane == 0) redm[wid] = m;
  __syncthreads();
  m = fmaxf(fmaxf(redm[0], redm[1]), fmaxf(redm[2], redm[3]));
  float e0 = expf(v.x - m), e1 = expf(v.y - m);
  float e2 = expf(v.z - m), e3 = expf(v.w - m);
  float s = e0 + e1 + e2 + e3;
  s = wave_sum(s);
  if (lane == 0) reds[wid] = s;
  __syncthreads();
  s = reds[0] + reds[1] + reds[2] + reds[3];
  const float inv = 1.0f / s;
  float4 o; o.x = e0*inv; o.y = e1*inv; o.z = e2*inv; o.w = e3*inv;
  *(float4*)&w[(size_t)b*C_ + t*4] = o;
}

// ---------------- final reduction, split over i (bf16 x, v) ----------------

__global__ __launch_bounds__(256) void final_part_kernel(
    const ushort* __restrict__ X, const ushort* __restrict__ V,
    const float* __restrict__ u, const float* __restrict__ w,
    const float* __restrict__ gamma, float* __restrict__ fpart)
{
  const int b = blockIdx.x, s = blockIdx.y;    // i in [s*16, s*16+16)
  const int d0 = threadIdx.x * 4;
  const ushort* xb = X + (size_t)b*C_*D_;
  const ushort* vb = V + (size_t)b*C_*D_;
  const float* ub = u + (size_t)b*C_;
  const float* wb = w + (size_t)b*C_;
  float4 av = {0,0,0,0}, ax = {0,0,0,0};
  #pragma unroll
  for (int ii = 0; ii < 16; ++ii) {
    const int i = s*16 + ii;
    const float ui = ub[i], wi = wb[i];
    ushort4 vv = *(const ushort4*)&vb[(size_t)i*D_ + d0];
    ushort4 xv = *(const ushort4*)&xb[(size_t)i*D_ + d0];
    av.x += ui*bf2f(vv.x); av.y += ui*bf2f(vv.y);
    av.z += ui*bf2f(vv.z); av.w += ui*bf2f(vv.w);
    ax.x += wi*bf2f(xv.x); ax.y += wi*bf2f(xv.y);
    ax.z += wi*bf2f(xv.z); ax.w += wi*bf2f(xv.w);
  }
  const float g = gamma[0];
  float4 o;
  o.x = g*av.x + ax.x; o.y = g*av.y + ax.y;
  o.z = g*av.z + ax.z; o.w = g*av.w + ax.w;
  *(float4*)&fpart[((size_t)s*B_ + b)*D_ + d0] = o;
}

__global__ __launch_bounds__(256) void final_combine_kernel(
    const float* __restrict__ fpart, float* __restrict__ out)
{
  const int idx = blockIdx.x*256 + threadIdx.x;   // over B_*D_
  float s = 0.f;
  #pragma unroll 8
  for (int sp = 0; sp < 64; ++sp) s += fpart[(size_t)sp*B_*D_ + idx];
  out[idx] = s;
}

extern "C" void kernel_launch(void* const* d_in, const int* in_sizes, int n_in,
                              void* d_out, int out_size, void* d_ws, size_t ws_size,
                              hipStream_t stream) {
  (void)in_sizes; (void)n_in; (void)out_size; (void)ws_size;
  const float* x  = (const float*)d_in[0];
  const float* Wf = (const float*)d_in[1];
  const float* bf = (const float*)d_in[2];
  const float* Wg = (const float*)d_in[3];
  const float* bg = (const float*)d_in[4];
  const float* Wx = (const float*)d_in[5];
  const float* bx = (const float*)d_in[6];
  const float* W1 = (const float*)d_in[7];
  const float* b1 = (const float*)d_in[8];
  const float* W2 = (const float*)d_in[9];
  const float* gamma = (const float*)d_in[11];
  float* out = (float*)d_out;

  // workspace layout (~170 MB total)
  ushort* x_bf = (ushort*)d_ws;                  // 32 MB
  ushort* wt   = x_bf + (size_t)M_*D_;           // 6 MB (Wf^T|Wg^T|Wx^T contiguous)
  ushort* w1t  = wt + (size_t)3*D_*D_;           // 128 KB
  ushort* q_bf = w1t + (size_t)H_*D_;            // 32 MB
  ushort* k_bf = q_bf + (size_t)M_*D_;           // 32 MB
  ushort* v_bf = k_bf + (size_t)M_*D_;           // 32 MB
  ushort* E    = v_bf + (size_t)M_*D_;           // 32 MB (bf16, all batches)
  float*  e2b  = (float*)(E + (size_t)B_*C_*C_); // 64 KB
  float*  wbuf = e2b + M_;                       // 64 KB
  float*  u    = wbuf + M_;                      // 64 KB
  float*  u_part = u + M_;                       // 4 MB
  float*  fpart  = u_part;                       // alias: u_part dead after u_combine

  // bf16 conversions
  cvt_kernel<<<dim3((M_*D_/4 + 255)/256), 256, 0, stream>>>(x, x_bf, M_*D_/4);
  tconv3_kernel<<<dim3(32,32,3), 256, 0, stream>>>(Wf, Wg, Wx, wt);
  tconv64_kernel<<<dim3(2,32), 256, 0, stream>>>(W1, w1t);

  // merged q/k/v projection (bf16 MFMA, N=3072)
  proj_kernel<<<dim3(24,128), 256, 0, stream>>>(x_bf, wt, bf, bg, bx,
                                                q_bf, k_bf, v_bf);

  // pooling weights (MFMA MLP + softmax)
  pool_mfma_kernel<<<dim3(M_/128), 256, 0, stream>>>(x_bf, w1t, b1, W2, e2b);
  softmax_w_kernel<<<dim3(B_), 256, 0, stream>>>(e2b, wbuf);

  // energy (bf16 MFMA, bf16 out) + fused softmax/colsum
  energy_kernel<<<dim3(8,8,B_), 256, 0, stream>>>(k_bf, q_bf, E);
  fused_sm_kernel<<<dim3(64,B_), 256, 0, stream>>>(E, wbuf, u_part);
  u_combine_kernel<<<dim3(M_/256), 256, 0, stream>>>(u_part, u);

  // final: split over i, then combine
  final_part_kernel<<<dim3(B_,64), 256, 0, stream>>>(x_bf, v_bf, u, wbuf, gamma, fpart);
  final_combine_kernel<<<dim3(M_/256), 256, 0, stream>>>(fpart, out);
}